// Round 1
// baseline (560.169 us; speedup 1.0000x reference)
//
#include <hip/hip_runtime.h>

// ---------------------------------------------------------------------------
// 3-layer GCN: per layer  h = x@W ; agg[i] = sum_{e: dst=i} norm_e * h[src_e]
//              (+ self loop) ; x' = relu(agg + b)
// CSR-by-dst built on device each call (deterministic work), gather-based
// aggregation (no float atomics).
// ---------------------------------------------------------------------------

__global__ void count_kernel(const int* __restrict__ ei, int* __restrict__ cnt, int E) {
    int e = blockIdx.x * blockDim.x + threadIdx.x;
    if (e < E) atomicAdd(&cnt[ei[E + e]], 1);   // dst row of edge_index
}

// single-block exclusive scan over cnt[0..n) -> rowptr/pos ; also dinv = rsqrt(cnt+1)
__global__ void scan_kernel(const int* __restrict__ cnt, int* __restrict__ rowptr,
                            int* __restrict__ pos, float* __restrict__ dinv, int n) {
    const int T = 256;
    int t = threadIdx.x;
    int CH = (n + T - 1) / T;
    int lo = t * CH;
    int hi = lo + CH;
    if (lo > n) lo = n;
    if (hi > n) hi = n;
    int s = 0;
    for (int i = lo; i < hi; ++i) s += cnt[i];
    __shared__ int part[T];
    part[t] = s;
    __syncthreads();
    // Hillis-Steele inclusive scan
    for (int off = 1; off < T; off <<= 1) {
        int v = (t >= off) ? part[t - off] : 0;
        __syncthreads();
        part[t] += v;
        __syncthreads();
    }
    int run = part[t] - s;   // exclusive prefix for this thread's chunk
    for (int i = lo; i < hi; ++i) {
        rowptr[i] = run;
        pos[i] = run;
        run += cnt[i];
        dinv[i] = rsqrtf((float)(cnt[i] + 1));   // +1 self loop
    }
    if (t == T - 1) rowptr[n] = run;
}

__global__ void fill_kernel(const int* __restrict__ ei, int* __restrict__ pos,
                            int* __restrict__ col, float* __restrict__ colw,
                            const float* __restrict__ dinv, int E) {
    int e = blockIdx.x * blockDim.x + threadIdx.x;
    if (e < E) {
        int s = ei[e];          // src
        int d = ei[E + e];      // dst
        int p = atomicAdd(&pos[d], 1);
        col[p]  = s;
        colw[p] = dinv[s];      // pre-gathered dinv[src]
    }
}

// H[n,128] = X[n,128] @ W[128,128]   (fp32, vector ALU; no fp32 MFMA on CDNA4)
// 64 rows per block, k split in 2 phases of 64 so LDS = 32KB(W) + 16KB(X) = 48KB
__global__ __launch_bounds__(256) void gemm128_kernel(const float* __restrict__ X,
                                                      const float* __restrict__ W,
                                                      float* __restrict__ H, int n) {
    __shared__ float Ws[64 * 128];
    __shared__ float Xs[64 * 64];
    int t = threadIdx.x;
    int row0 = blockIdx.x * 64;
    int tx = t & 31, ty = t >> 5;
    int c0 = tx * 4, r0 = ty * 8;

    float4 acc[8];
#pragma unroll
    for (int r = 0; r < 8; ++r) acc[r] = make_float4(0.f, 0.f, 0.f, 0.f);

    for (int kp = 0; kp < 2; ++kp) {
        {   // stage W slice: rows kp*64..+63, all 128 cols (8192 floats)
            const float4* W4 = (const float4*)(W + kp * 64 * 128);
            float4* Ws4 = (float4*)Ws;
#pragma unroll
            for (int i = 0; i < 8; ++i) Ws4[t + 256 * i] = W4[t + 256 * i];
        }
        {   // stage X tile: rows row0..+63, cols kp*64..+63 (64x64)
            float4* Xs4 = (float4*)Xs;
#pragma unroll
            for (int i = 0; i < 4; ++i) {
                int idx = t + 256 * i;           // 0..1023, 16 float4 per row
                int r = idx >> 4, c4 = idx & 15;
                int row = row0 + r;
                float4 v = make_float4(0.f, 0.f, 0.f, 0.f);
                if (row < n) v = *(const float4*)(X + (size_t)row * 128 + kp * 64 + c4 * 4);
                Xs4[idx] = v;
            }
        }
        __syncthreads();
        for (int k = 0; k < 64; k += 4) {
            float4 w0 = *(const float4*)&Ws[(k + 0) * 128 + c0];
            float4 w1 = *(const float4*)&Ws[(k + 1) * 128 + c0];
            float4 w2 = *(const float4*)&Ws[(k + 2) * 128 + c0];
            float4 w3 = *(const float4*)&Ws[(k + 3) * 128 + c0];
#pragma unroll
            for (int r = 0; r < 8; ++r) {
                float4 xv = *(const float4*)&Xs[(r0 + r) * 64 + k];
                acc[r].x = fmaf(xv.x, w0.x, fmaf(xv.y, w1.x, fmaf(xv.z, w2.x, fmaf(xv.w, w3.x, acc[r].x))));
                acc[r].y = fmaf(xv.x, w0.y, fmaf(xv.y, w1.y, fmaf(xv.z, w2.y, fmaf(xv.w, w3.y, acc[r].y))));
                acc[r].z = fmaf(xv.x, w0.z, fmaf(xv.y, w1.z, fmaf(xv.z, w2.z, fmaf(xv.w, w3.z, acc[r].z))));
                acc[r].w = fmaf(xv.x, w0.w, fmaf(xv.y, w1.w, fmaf(xv.z, w2.w, fmaf(xv.w, w3.w, acc[r].w))));
            }
        }
        __syncthreads();
    }
#pragma unroll
    for (int r = 0; r < 8; ++r) {
        int row = row0 + r0 + r;
        if (row < n) *(float4*)(H + (size_t)row * 128 + c0) = acc[r];
    }
}

// one wave per node; lane owns features {2*lane, 2*lane+1}
__global__ __launch_bounds__(256) void agg_kernel(const float* __restrict__ H,
                                                  const int* __restrict__ rowptr,
                                                  const int* __restrict__ col,
                                                  const float* __restrict__ colw,
                                                  const float* __restrict__ dinv,
                                                  const float* __restrict__ b,
                                                  float* __restrict__ out, int n) {
    int gw = (int)((blockIdx.x * blockDim.x + threadIdx.x) >> 6);
    int lane = threadIdx.x & 63;
    if (gw >= n) return;
    int beg = rowptr[gw], end = rowptr[gw + 1];
    float di = dinv[gw];
    const float2* H2 = (const float2*)H;

    float ax0 = 0.f, ay0 = 0.f, ax1 = 0.f, ay1 = 0.f;
    int e = beg;
    for (; e + 1 < end; e += 2) {
        int s0 = col[e], s1 = col[e + 1];
        float w0 = colw[e], w1 = colw[e + 1];
        float2 h0 = H2[(size_t)s0 * 64 + lane];
        float2 h1 = H2[(size_t)s1 * 64 + lane];
        ax0 = fmaf(w0, h0.x, ax0); ay0 = fmaf(w0, h0.y, ay0);
        ax1 = fmaf(w1, h1.x, ax1); ay1 = fmaf(w1, h1.y, ay1);
    }
    if (e < end) {
        int s0 = col[e];
        float w0 = colw[e];
        float2 h0 = H2[(size_t)s0 * 64 + lane];
        ax0 = fmaf(w0, h0.x, ax0); ay0 = fmaf(w0, h0.y, ay0);
    }
    float2 hi = H2[(size_t)gw * 64 + lane];
    float sx = (ax0 + ax1 + di * hi.x) * di;   // di*(sum + di*h_i)
    float sy = (ay0 + ay1 + di * hi.y) * di;
    float2 bv = ((const float2*)b)[lane];
    float2 o;
    o.x = fmaxf(sx + bv.x, 0.f);
    o.y = fmaxf(sy + bv.y, 0.f);
    ((float2*)out)[(size_t)gw * 64 + lane] = o;
}

extern "C" void kernel_launch(void* const* d_in, const int* in_sizes, int n_in,
                              void* d_out, int out_size, void* d_ws, size_t ws_size,
                              hipStream_t stream) {
    const float* x  = (const float*)d_in[0];
    const int*   ei = (const int*)d_in[1];
    const float* W0 = (const float*)d_in[2];
    const float* b0 = (const float*)d_in[3];
    const float* W1 = (const float*)d_in[4];
    const float* b1 = (const float*)d_in[5];
    const float* W2 = (const float*)d_in[6];
    const float* b2 = (const float*)d_in[7];
    float* out = (float*)d_out;

    int N = in_sizes[0] / 128;
    int E = in_sizes[1] / 2;

    char* wsb = (char*)d_ws;
    size_t off = 0;
    auto alloc = [&](size_t bytes) -> void* {
        void* p = wsb + off;
        off = (off + bytes + 255) & ~(size_t)255;
        return p;
    };
    int*   cnt    = (int*)  alloc((size_t)N * 4);
    int*   rowptr = (int*)  alloc((size_t)(N + 1) * 4);
    int*   pos    = (int*)  alloc((size_t)N * 4);
    float* dinv   = (float*)alloc((size_t)N * 4);
    int*   col    = (int*)  alloc((size_t)E * 4);
    float* colw   = (float*)alloc((size_t)E * 4);
    float* h      = (float*)alloc((size_t)N * 128 * 4);
    float* xA     = (float*)alloc((size_t)N * 128 * 4);

    hipMemsetAsync(cnt, 0, (size_t)N * 4, stream);
    count_kernel<<<(E + 255) / 256, 256, 0, stream>>>(ei, cnt, E);
    scan_kernel<<<1, 256, 0, stream>>>(cnt, rowptr, pos, dinv, N);
    fill_kernel<<<(E + 255) / 256, 256, 0, stream>>>(ei, pos, col, colw, dinv, E);

    int gblk = (N + 63) / 64;
    int ablk = (N + 3) / 4;   // 4 waves (nodes) per 256-thread block

    gemm128_kernel<<<gblk, 256, 0, stream>>>(x,  W0, h, N);
    agg_kernel<<<ablk, 256, 0, stream>>>(h, rowptr, col, colw, dinv, b0, xA, N);

    gemm128_kernel<<<gblk, 256, 0, stream>>>(xA, W1, h, N);
    agg_kernel<<<ablk, 256, 0, stream>>>(h, rowptr, col, colw, dinv, b1, xA, N);

    gemm128_kernel<<<gblk, 256, 0, stream>>>(xA, W2, h, N);
    agg_kernel<<<ablk, 256, 0, stream>>>(h, rowptr, col, colw, dinv, b2, out, N);
}

// Round 2
// 422.890 us; speedup vs baseline: 1.3246x; 1.3246x over previous
//
#include <hip/hip_runtime.h>

// ---------------------------------------------------------------------------
// 3-layer GCN: per layer  h = x@W ; agg[i] = sum_{e: dst=i} norm_e * h[src_e]
//              (+ self loop) ; x' = relu(agg + b)
// CSR-by-dst built on device each call; gather-based aggregation (no float
// atomics). R1: hierarchical 3-kernel scan replaces the 148us single-block scan.
// ---------------------------------------------------------------------------

__global__ void count_kernel(const int* __restrict__ ei, int* __restrict__ cnt, int E) {
    int e = blockIdx.x * blockDim.x + threadIdx.x;
    if (e < E) atomicAdd(&cnt[ei[E + e]], 1);   // dst row of edge_index
}

// k1: per-block (256-elem) sums of cnt
__global__ __launch_bounds__(256) void block_sum_kernel(const int* __restrict__ cnt,
                                                        int* __restrict__ bsum, int n) {
    int i = blockIdx.x * 256 + threadIdx.x;
    int v = (i < n) ? cnt[i] : 0;
#pragma unroll
    for (int off = 32; off; off >>= 1) v += __shfl_down(v, off);
    __shared__ int ws[4];
    int lane = threadIdx.x & 63, w = threadIdx.x >> 6;
    if (lane == 0) ws[w] = v;
    __syncthreads();
    if (threadIdx.x == 0) bsum[blockIdx.x] = ws[0] + ws[1] + ws[2] + ws[3];
}

// k2: single block scans the <=256 partials; also writes rowptr[n] (total)
__global__ __launch_bounds__(256) void scan_partials_kernel(const int* __restrict__ bsum,
                                                            int* __restrict__ bpre,
                                                            int* __restrict__ rowptr,
                                                            int nb, int n) {
    __shared__ int sh[256];
    int t = threadIdx.x;
    int v = (t < nb) ? bsum[t] : 0;
    sh[t] = v;
    __syncthreads();
    for (int off = 1; off < 256; off <<= 1) {
        int u = (t >= off) ? sh[t - off] : 0;
        __syncthreads();
        sh[t] += u;
        __syncthreads();
    }
    if (t < nb) bpre[t] = sh[t] - v;   // exclusive block prefix
    if (t == 255) rowptr[n] = sh[255];
}

// k3: block-local exclusive scan + block prefix -> rowptr/pos; dinv = rsqrt(cnt+1)
__global__ __launch_bounds__(256) void scan_write_kernel(const int* __restrict__ cnt,
                                                         const int* __restrict__ bpre,
                                                         int* __restrict__ rowptr,
                                                         int* __restrict__ pos,
                                                         float* __restrict__ dinv, int n) {
    __shared__ int sh[256];
    int t = threadIdx.x;
    int i = blockIdx.x * 256 + t;
    int c = (i < n) ? cnt[i] : 0;
    sh[t] = c;
    __syncthreads();
    for (int off = 1; off < 256; off <<= 1) {
        int u = (t >= off) ? sh[t - off] : 0;
        __syncthreads();
        sh[t] += u;
        __syncthreads();
    }
    if (i < n) {
        int ex = bpre[blockIdx.x] + sh[t] - c;
        rowptr[i] = ex;
        pos[i] = ex;
        dinv[i] = rsqrtf((float)(c + 1));   // +1 self loop
    }
}

__global__ void fill_kernel(const int* __restrict__ ei, int* __restrict__ pos,
                            int* __restrict__ col, float* __restrict__ colw,
                            const float* __restrict__ dinv, int E) {
    int e = blockIdx.x * blockDim.x + threadIdx.x;
    if (e < E) {
        int s = ei[e];          // src
        int d = ei[E + e];      // dst
        int p = atomicAdd(&pos[d], 1);
        col[p]  = s;
        colw[p] = dinv[s];      // pre-gathered dinv[src]
    }
}

// H[n,128] = X[n,128] @ W[128,128]   (fp32, vector ALU; no fp32 MFMA on CDNA4)
__global__ __launch_bounds__(256) void gemm128_kernel(const float* __restrict__ X,
                                                      const float* __restrict__ W,
                                                      float* __restrict__ H, int n) {
    __shared__ float Ws[64 * 128];
    __shared__ float Xs[64 * 64];
    int t = threadIdx.x;
    int row0 = blockIdx.x * 64;
    int tx = t & 31, ty = t >> 5;
    int c0 = tx * 4, r0 = ty * 8;

    float4 acc[8];
#pragma unroll
    for (int r = 0; r < 8; ++r) acc[r] = make_float4(0.f, 0.f, 0.f, 0.f);

    for (int kp = 0; kp < 2; ++kp) {
        {   // stage W slice: rows kp*64..+63, all 128 cols
            const float4* W4 = (const float4*)(W + kp * 64 * 128);
            float4* Ws4 = (float4*)Ws;
#pragma unroll
            for (int i = 0; i < 8; ++i) Ws4[t + 256 * i] = W4[t + 256 * i];
        }
        {   // stage X tile: rows row0..+63, cols kp*64..+63
            float4* Xs4 = (float4*)Xs;
#pragma unroll
            for (int i = 0; i < 4; ++i) {
                int idx = t + 256 * i;
                int r = idx >> 4, c4 = idx & 15;
                int row = row0 + r;
                float4 v = make_float4(0.f, 0.f, 0.f, 0.f);
                if (row < n) v = *(const float4*)(X + (size_t)row * 128 + kp * 64 + c4 * 4);
                Xs4[idx] = v;
            }
        }
        __syncthreads();
        for (int k = 0; k < 64; k += 4) {
            float4 w0 = *(const float4*)&Ws[(k + 0) * 128 + c0];
            float4 w1 = *(const float4*)&Ws[(k + 1) * 128 + c0];
            float4 w2 = *(const float4*)&Ws[(k + 2) * 128 + c0];
            float4 w3 = *(const float4*)&Ws[(k + 3) * 128 + c0];
#pragma unroll
            for (int r = 0; r < 8; ++r) {
                float4 xv = *(const float4*)&Xs[(r0 + r) * 64 + k];
                acc[r].x = fmaf(xv.x, w0.x, fmaf(xv.y, w1.x, fmaf(xv.z, w2.x, fmaf(xv.w, w3.x, acc[r].x))));
                acc[r].y = fmaf(xv.x, w0.y, fmaf(xv.y, w1.y, fmaf(xv.z, w2.y, fmaf(xv.w, w3.y, acc[r].y))));
                acc[r].z = fmaf(xv.x, w0.z, fmaf(xv.y, w1.z, fmaf(xv.z, w2.z, fmaf(xv.w, w3.z, acc[r].z))));
                acc[r].w = fmaf(xv.x, w0.w, fmaf(xv.y, w1.w, fmaf(xv.z, w2.w, fmaf(xv.w, w3.w, acc[r].w))));
            }
        }
        __syncthreads();
    }
#pragma unroll
    for (int r = 0; r < 8; ++r) {
        int row = row0 + r0 + r;
        if (row < n) *(float4*)(H + (size_t)row * 128 + c0) = acc[r];
    }
}

// one wave per node; lane owns features {2*lane, 2*lane+1}
__global__ __launch_bounds__(256) void agg_kernel(const float* __restrict__ H,
                                                  const int* __restrict__ rowptr,
                                                  const int* __restrict__ col,
                                                  const float* __restrict__ colw,
                                                  const float* __restrict__ dinv,
                                                  const float* __restrict__ b,
                                                  float* __restrict__ out, int n) {
    int gw = (int)((blockIdx.x * blockDim.x + threadIdx.x) >> 6);
    int lane = threadIdx.x & 63;
    if (gw >= n) return;
    int beg = rowptr[gw], end = rowptr[gw + 1];
    float di = dinv[gw];
    const float2* H2 = (const float2*)H;

    float ax0 = 0.f, ay0 = 0.f, ax1 = 0.f, ay1 = 0.f;
    int e = beg;
    for (; e + 1 < end; e += 2) {
        int s0 = col[e], s1 = col[e + 1];
        float w0 = colw[e], w1 = colw[e + 1];
        float2 h0 = H2[(size_t)s0 * 64 + lane];
        float2 h1 = H2[(size_t)s1 * 64 + lane];
        ax0 = fmaf(w0, h0.x, ax0); ay0 = fmaf(w0, h0.y, ay0);
        ax1 = fmaf(w1, h1.x, ax1); ay1 = fmaf(w1, h1.y, ay1);
    }
    if (e < end) {
        int s0 = col[e];
        float w0 = colw[e];
        float2 h0 = H2[(size_t)s0 * 64 + lane];
        ax0 = fmaf(w0, h0.x, ax0); ay0 = fmaf(w0, h0.y, ay0);
    }
    float2 hi = H2[(size_t)gw * 64 + lane];
    float sx = (ax0 + ax1 + di * hi.x) * di;   // di*(sum + di*h_i)
    float sy = (ay0 + ay1 + di * hi.y) * di;
    float2 bv = ((const float2*)b)[lane];
    float2 o;
    o.x = fmaxf(sx + bv.x, 0.f);
    o.y = fmaxf(sy + bv.y, 0.f);
    ((float2*)out)[(size_t)gw * 64 + lane] = o;
}

extern "C" void kernel_launch(void* const* d_in, const int* in_sizes, int n_in,
                              void* d_out, int out_size, void* d_ws, size_t ws_size,
                              hipStream_t stream) {
    const float* x  = (const float*)d_in[0];
    const int*   ei = (const int*)d_in[1];
    const float* W0 = (const float*)d_in[2];
    const float* b0 = (const float*)d_in[3];
    const float* W1 = (const float*)d_in[4];
    const float* b1 = (const float*)d_in[5];
    const float* W2 = (const float*)d_in[6];
    const float* b2 = (const float*)d_in[7];
    float* out = (float*)d_out;

    int N = in_sizes[0] / 128;
    int E = in_sizes[1] / 2;
    int nb = (N + 255) / 256;   // scan blocks (196 for N=50000, fits k2's 256)

    char* wsb = (char*)d_ws;
    size_t off = 0;
    auto alloc = [&](size_t bytes) -> void* {
        void* p = wsb + off;
        off = (off + bytes + 255) & ~(size_t)255;
        return p;
    };
    int*   cnt    = (int*)  alloc((size_t)N * 4);
    int*   rowptr = (int*)  alloc((size_t)(N + 1) * 4);
    int*   pos    = (int*)  alloc((size_t)N * 4);
    float* dinv   = (float*)alloc((size_t)N * 4);
    int*   bsum   = (int*)  alloc((size_t)nb * 4);
    int*   bpre   = (int*)  alloc((size_t)nb * 4);
    int*   col    = (int*)  alloc((size_t)E * 4);
    float* colw   = (float*)alloc((size_t)E * 4);
    float* h      = (float*)alloc((size_t)N * 128 * 4);
    float* xA     = (float*)alloc((size_t)N * 128 * 4);

    hipMemsetAsync(cnt, 0, (size_t)N * 4, stream);
    count_kernel<<<(E + 255) / 256, 256, 0, stream>>>(ei, cnt, E);
    block_sum_kernel<<<nb, 256, 0, stream>>>(cnt, bsum, N);
    scan_partials_kernel<<<1, 256, 0, stream>>>(bsum, bpre, rowptr, nb, N);
    scan_write_kernel<<<nb, 256, 0, stream>>>(cnt, bpre, rowptr, pos, dinv, N);
    fill_kernel<<<(E + 255) / 256, 256, 0, stream>>>(ei, pos, col, colw, dinv, E);

    int gblk = (N + 63) / 64;
    int ablk = (N + 3) / 4;   // 4 waves (nodes) per 256-thread block

    gemm128_kernel<<<gblk, 256, 0, stream>>>(x,  W0, h, N);
    agg_kernel<<<ablk, 256, 0, stream>>>(h, rowptr, col, colw, dinv, b0, xA, N);

    gemm128_kernel<<<gblk, 256, 0, stream>>>(xA, W1, h, N);
    agg_kernel<<<ablk, 256, 0, stream>>>(h, rowptr, col, colw, dinv, b1, xA, N);

    gemm128_kernel<<<gblk, 256, 0, stream>>>(xA, W2, h, N);
    agg_kernel<<<ablk, 256, 0, stream>>>(h, rowptr, col, colw, dinv, b2, out, N);
}

// Round 3
// 371.975 us; speedup vs baseline: 1.5059x; 1.1369x over previous
//
#include <hip/hip_runtime.h>

// ---------------------------------------------------------------------------
// 3-layer GCN: per layer  h = x@W ; agg[i] = sum_{e: dst=i} norm_e * h[src_e]
//              (+ self loop) ; x' = relu(agg + b)
// CSR-by-dst built on device each call; gather-based aggregation (no float
// atomics). R2: agg gathers float4/lane, 2 edges per instruction, packed
// {col,w} edge records, 4 edges in flight per wave.
// ---------------------------------------------------------------------------

struct EData { int col; float w; };   // 8B packed edge record

__global__ void count_kernel(const int* __restrict__ ei, int* __restrict__ cnt, int E) {
    int e = blockIdx.x * blockDim.x + threadIdx.x;
    if (e < E) atomicAdd(&cnt[ei[E + e]], 1);   // dst row of edge_index
}

// k1: per-block (256-elem) sums of cnt
__global__ __launch_bounds__(256) void block_sum_kernel(const int* __restrict__ cnt,
                                                        int* __restrict__ bsum, int n) {
    int i = blockIdx.x * 256 + threadIdx.x;
    int v = (i < n) ? cnt[i] : 0;
#pragma unroll
    for (int off = 32; off; off >>= 1) v += __shfl_down(v, off);
    __shared__ int ws[4];
    int lane = threadIdx.x & 63, w = threadIdx.x >> 6;
    if (lane == 0) ws[w] = v;
    __syncthreads();
    if (threadIdx.x == 0) bsum[blockIdx.x] = ws[0] + ws[1] + ws[2] + ws[3];
}

// k2: single block scans the <=256 partials; also writes rowptr[n] (total)
__global__ __launch_bounds__(256) void scan_partials_kernel(const int* __restrict__ bsum,
                                                            int* __restrict__ bpre,
                                                            int* __restrict__ rowptr,
                                                            int nb, int n) {
    __shared__ int sh[256];
    int t = threadIdx.x;
    int v = (t < nb) ? bsum[t] : 0;
    sh[t] = v;
    __syncthreads();
    for (int off = 1; off < 256; off <<= 1) {
        int u = (t >= off) ? sh[t - off] : 0;
        __syncthreads();
        sh[t] += u;
        __syncthreads();
    }
    if (t < nb) bpre[t] = sh[t] - v;   // exclusive block prefix
    if (t == 255) rowptr[n] = sh[255];
}

// k3: block-local exclusive scan + block prefix -> rowptr/pos; dinv = rsqrt(cnt+1)
__global__ __launch_bounds__(256) void scan_write_kernel(const int* __restrict__ cnt,
                                                         const int* __restrict__ bpre,
                                                         int* __restrict__ rowptr,
                                                         int* __restrict__ pos,
                                                         float* __restrict__ dinv, int n) {
    __shared__ int sh[256];
    int t = threadIdx.x;
    int i = blockIdx.x * 256 + t;
    int c = (i < n) ? cnt[i] : 0;
    sh[t] = c;
    __syncthreads();
    for (int off = 1; off < 256; off <<= 1) {
        int u = (t >= off) ? sh[t - off] : 0;
        __syncthreads();
        sh[t] += u;
        __syncthreads();
    }
    if (i < n) {
        int ex = bpre[blockIdx.x] + sh[t] - c;
        rowptr[i] = ex;
        pos[i] = ex;
        dinv[i] = rsqrtf((float)(c + 1));   // +1 self loop
    }
}

__global__ void fill_kernel(const int* __restrict__ ei, int* __restrict__ pos,
                            EData* __restrict__ ed,
                            const float* __restrict__ dinv, int E) {
    int e = blockIdx.x * blockDim.x + threadIdx.x;
    if (e < E) {
        int s = ei[e];          // src
        int d = ei[E + e];      // dst
        int p = atomicAdd(&pos[d], 1);
        EData r; r.col = s; r.w = dinv[s];
        ed[p] = r;
    }
}

// H[n,128] = X[n,128] @ W[128,128]   (fp32, vector ALU; no fp32 MFMA on CDNA4)
__global__ __launch_bounds__(256) void gemm128_kernel(const float* __restrict__ X,
                                                      const float* __restrict__ W,
                                                      float* __restrict__ H, int n) {
    __shared__ float Ws[64 * 128];
    __shared__ float Xs[64 * 64];
    int t = threadIdx.x;
    int row0 = blockIdx.x * 64;
    int tx = t & 31, ty = t >> 5;
    int c0 = tx * 4, r0 = ty * 8;

    float4 acc[8];
#pragma unroll
    for (int r = 0; r < 8; ++r) acc[r] = make_float4(0.f, 0.f, 0.f, 0.f);

    for (int kp = 0; kp < 2; ++kp) {
        {   // stage W slice: rows kp*64..+63, all 128 cols
            const float4* W4 = (const float4*)(W + kp * 64 * 128);
            float4* Ws4 = (float4*)Ws;
#pragma unroll
            for (int i = 0; i < 8; ++i) Ws4[t + 256 * i] = W4[t + 256 * i];
        }
        {   // stage X tile: rows row0..+63, cols kp*64..+63
            float4* Xs4 = (float4*)Xs;
#pragma unroll
            for (int i = 0; i < 4; ++i) {
                int idx = t + 256 * i;
                int r = idx >> 4, c4 = idx & 15;
                int row = row0 + r;
                float4 v = make_float4(0.f, 0.f, 0.f, 0.f);
                if (row < n) v = *(const float4*)(X + (size_t)row * 128 + kp * 64 + c4 * 4);
                Xs4[idx] = v;
            }
        }
        __syncthreads();
        for (int k = 0; k < 64; k += 4) {
            float4 w0 = *(const float4*)&Ws[(k + 0) * 128 + c0];
            float4 w1 = *(const float4*)&Ws[(k + 1) * 128 + c0];
            float4 w2 = *(const float4*)&Ws[(k + 2) * 128 + c0];
            float4 w3 = *(const float4*)&Ws[(k + 3) * 128 + c0];
#pragma unroll
            for (int r = 0; r < 8; ++r) {
                float4 xv = *(const float4*)&Xs[(r0 + r) * 64 + k];
                acc[r].x = fmaf(xv.x, w0.x, fmaf(xv.y, w1.x, fmaf(xv.z, w2.x, fmaf(xv.w, w3.x, acc[r].x))));
                acc[r].y = fmaf(xv.x, w0.y, fmaf(xv.y, w1.y, fmaf(xv.z, w2.y, fmaf(xv.w, w3.y, acc[r].y))));
                acc[r].z = fmaf(xv.x, w0.z, fmaf(xv.y, w1.z, fmaf(xv.z, w2.z, fmaf(xv.w, w3.z, acc[r].z))));
                acc[r].w = fmaf(xv.x, w0.w, fmaf(xv.y, w1.w, fmaf(xv.z, w2.w, fmaf(xv.w, w3.w, acc[r].w))));
            }
        }
        __syncthreads();
    }
#pragma unroll
    for (int r = 0; r < 8; ++r) {
        int row = row0 + r0 + r;
        if (row < n) *(float4*)(H + (size_t)row * 128 + c0) = acc[r];
    }
}

// one wave per node; lane layout: q=lane&31 -> feature quad (float4),
// p=lane>>5 -> edge parity. One gather instruction = 2 full 512B rows.
__global__ __launch_bounds__(256) void agg_kernel(const float* __restrict__ H,
                                                  const int* __restrict__ rowptr,
                                                  const EData* __restrict__ ed,
                                                  const float* __restrict__ dinv,
                                                  const float* __restrict__ b,
                                                  float* __restrict__ out, int n) {
    int gw = (int)((blockIdx.x * blockDim.x + threadIdx.x) >> 6);
    if (gw >= n) return;
    int lane = threadIdx.x & 63;
    int q = lane & 31, p = lane >> 5;
    int beg = rowptr[gw], end = rowptr[gw + 1];
    float di = dinv[gw];
    const float4* H4 = (const float4*)H;

    float4 a0 = make_float4(0.f, 0.f, 0.f, 0.f);
    float4 a1 = make_float4(0.f, 0.f, 0.f, 0.f);

    int e = beg;
    for (; e + 4 <= end; e += 4) {                 // 2 pairs (4 edges) in flight
        EData d0 = ed[e + p];
        EData d1 = ed[e + 2 + p];
        float4 h0 = H4[(size_t)d0.col * 32 + q];
        float4 h1 = H4[(size_t)d1.col * 32 + q];
        a0.x = fmaf(d0.w, h0.x, a0.x); a0.y = fmaf(d0.w, h0.y, a0.y);
        a0.z = fmaf(d0.w, h0.z, a0.z); a0.w = fmaf(d0.w, h0.w, a0.w);
        a1.x = fmaf(d1.w, h1.x, a1.x); a1.y = fmaf(d1.w, h1.y, a1.y);
        a1.z = fmaf(d1.w, h1.z, a1.z); a1.w = fmaf(d1.w, h1.w, a1.w);
    }
    for (; e < end; e += 2) {                      // remainder (masked pair)
        int idx = e + p;
        bool valid = idx < end;
        EData d0 = ed[valid ? idx : e];
        float w = valid ? d0.w : 0.f;
        float4 h0 = H4[(size_t)d0.col * 32 + q];
        a0.x = fmaf(w, h0.x, a0.x); a0.y = fmaf(w, h0.y, a0.y);
        a0.z = fmaf(w, h0.z, a0.z); a0.w = fmaf(w, h0.w, a0.w);
    }
    a0.x += a1.x; a0.y += a1.y; a0.z += a1.z; a0.w += a1.w;
    // combine parity halves (lane ^ 32)
    a0.x += __shfl_xor(a0.x, 32);
    a0.y += __shfl_xor(a0.y, 32);
    a0.z += __shfl_xor(a0.z, 32);
    a0.w += __shfl_xor(a0.w, 32);

    if (p == 0) {
        float4 hi = H4[(size_t)gw * 32 + q];
        float4 bv = ((const float4*)b)[q];
        float4 o;
        o.x = fmaxf((a0.x + di * hi.x) * di + bv.x, 0.f);
        o.y = fmaxf((a0.y + di * hi.y) * di + bv.y, 0.f);
        o.z = fmaxf((a0.z + di * hi.z) * di + bv.z, 0.f);
        o.w = fmaxf((a0.w + di * hi.w) * di + bv.w, 0.f);
        ((float4*)out)[(size_t)gw * 32 + q] = o;
    }
}

extern "C" void kernel_launch(void* const* d_in, const int* in_sizes, int n_in,
                              void* d_out, int out_size, void* d_ws, size_t ws_size,
                              hipStream_t stream) {
    const float* x  = (const float*)d_in[0];
    const int*   ei = (const int*)d_in[1];
    const float* W0 = (const float*)d_in[2];
    const float* b0 = (const float*)d_in[3];
    const float* W1 = (const float*)d_in[4];
    const float* b1 = (const float*)d_in[5];
    const float* W2 = (const float*)d_in[6];
    const float* b2 = (const float*)d_in[7];
    float* out = (float*)d_out;

    int N = in_sizes[0] / 128;
    int E = in_sizes[1] / 2;
    int nb = (N + 255) / 256;   // scan blocks (196 for N=50000, fits k2's 256)

    char* wsb = (char*)d_ws;
    size_t off = 0;
    auto alloc = [&](size_t bytes) -> void* {
        void* p = wsb + off;
        off = (off + bytes + 255) & ~(size_t)255;
        return p;
    };
    int*   cnt    = (int*)  alloc((size_t)N * 4);
    int*   rowptr = (int*)  alloc((size_t)(N + 1) * 4);
    int*   pos    = (int*)  alloc((size_t)N * 4);
    float* dinv   = (float*)alloc((size_t)N * 4);
    int*   bsum   = (int*)  alloc((size_t)nb * 4);
    int*   bpre   = (int*)  alloc((size_t)nb * 4);
    EData* ed     = (EData*)alloc((size_t)E * 8);
    float* h      = (float*)alloc((size_t)N * 128 * 4);
    float* xA     = (float*)alloc((size_t)N * 128 * 4);

    hipMemsetAsync(cnt, 0, (size_t)N * 4, stream);
    count_kernel<<<(E + 255) / 256, 256, 0, stream>>>(ei, cnt, E);
    block_sum_kernel<<<nb, 256, 0, stream>>>(cnt, bsum, N);
    scan_partials_kernel<<<1, 256, 0, stream>>>(bsum, bpre, rowptr, nb, N);
    scan_write_kernel<<<nb, 256, 0, stream>>>(cnt, bpre, rowptr, pos, dinv, N);
    fill_kernel<<<(E + 255) / 256, 256, 0, stream>>>(ei, pos, ed, dinv, E);

    int gblk = (N + 63) / 64;
    int ablk = (N + 3) / 4;   // 4 waves (nodes) per 256-thread block

    gemm128_kernel<<<gblk, 256, 0, stream>>>(x,  W0, h, N);
    agg_kernel<<<ablk, 256, 0, stream>>>(h, rowptr, ed, dinv, b0, xA, N);

    gemm128_kernel<<<gblk, 256, 0, stream>>>(xA, W1, h, N);
    agg_kernel<<<ablk, 256, 0, stream>>>(h, rowptr, ed, dinv, b1, xA, N);

    gemm128_kernel<<<gblk, 256, 0, stream>>>(xA, W2, h, N);
    agg_kernel<<<ablk, 256, 0, stream>>>(h, rowptr, ed, dinv, b2, out, N);
}

// Round 4
// 299.892 us; speedup vs baseline: 1.8679x; 1.2404x over previous
//
#include <hip/hip_runtime.h>

// ---------------------------------------------------------------------------
// 3-layer GCN: per layer  h = x@W ; agg[i] = sum_{e: dst=i} norm_e * h[src_e]
//              (+ self loop) ; x' = relu(agg + b)
// R3: h stored bf16 (256B rows) -> gather traffic halved; one 16B/lane gather
// covers 4 edges' rows; 8 edges in flight per wave.
// ---------------------------------------------------------------------------

typedef __attribute__((ext_vector_type(8))) unsigned short ushort8;
typedef __attribute__((ext_vector_type(4))) unsigned short ushort4v;

struct EData { int col; float w; };   // 8B packed edge record

__device__ __forceinline__ unsigned short f2bf(float f) {
    unsigned u = __float_as_uint(f);
    unsigned r = (u + 0x7FFF + ((u >> 16) & 1)) >> 16;   // RNE
    return (unsigned short)r;
}
__device__ __forceinline__ float bf2f(unsigned short s) {
    return __uint_as_float(((unsigned)s) << 16);
}

__global__ void count_kernel(const int* __restrict__ ei, int* __restrict__ cnt, int E) {
    int e = blockIdx.x * blockDim.x + threadIdx.x;
    if (e < E) atomicAdd(&cnt[ei[E + e]], 1);   // dst row of edge_index
}

__global__ __launch_bounds__(256) void block_sum_kernel(const int* __restrict__ cnt,
                                                        int* __restrict__ bsum, int n) {
    int i = blockIdx.x * 256 + threadIdx.x;
    int v = (i < n) ? cnt[i] : 0;
#pragma unroll
    for (int off = 32; off; off >>= 1) v += __shfl_down(v, off);
    __shared__ int ws[4];
    int lane = threadIdx.x & 63, w = threadIdx.x >> 6;
    if (lane == 0) ws[w] = v;
    __syncthreads();
    if (threadIdx.x == 0) bsum[blockIdx.x] = ws[0] + ws[1] + ws[2] + ws[3];
}

__global__ __launch_bounds__(256) void scan_partials_kernel(const int* __restrict__ bsum,
                                                            int* __restrict__ bpre,
                                                            int* __restrict__ rowptr,
                                                            int nb, int n) {
    __shared__ int sh[256];
    int t = threadIdx.x;
    int v = (t < nb) ? bsum[t] : 0;
    sh[t] = v;
    __syncthreads();
    for (int off = 1; off < 256; off <<= 1) {
        int u = (t >= off) ? sh[t - off] : 0;
        __syncthreads();
        sh[t] += u;
        __syncthreads();
    }
    if (t < nb) bpre[t] = sh[t] - v;
    if (t == 255) rowptr[n] = sh[255];
}

__global__ __launch_bounds__(256) void scan_write_kernel(const int* __restrict__ cnt,
                                                         const int* __restrict__ bpre,
                                                         int* __restrict__ rowptr,
                                                         int* __restrict__ pos,
                                                         float* __restrict__ dinv, int n) {
    __shared__ int sh[256];
    int t = threadIdx.x;
    int i = blockIdx.x * 256 + t;
    int c = (i < n) ? cnt[i] : 0;
    sh[t] = c;
    __syncthreads();
    for (int off = 1; off < 256; off <<= 1) {
        int u = (t >= off) ? sh[t - off] : 0;
        __syncthreads();
        sh[t] += u;
        __syncthreads();
    }
    if (i < n) {
        int ex = bpre[blockIdx.x] + sh[t] - c;
        rowptr[i] = ex;
        pos[i] = ex;
        dinv[i] = rsqrtf((float)(c + 1));   // +1 self loop
    }
}

__global__ void fill_kernel(const int* __restrict__ ei, int* __restrict__ pos,
                            EData* __restrict__ ed,
                            const float* __restrict__ dinv, int E) {
    int e = blockIdx.x * blockDim.x + threadIdx.x;
    if (e < E) {
        int s = ei[e];
        int d = ei[E + e];
        int p = atomicAdd(&pos[d], 1);
        EData r; r.col = s; r.w = dinv[s];
        ed[p] = r;
    }
}

// H[n,128](bf16) = X[n,128](f32) @ W[128,128](f32) ; fp32 FMA, bf16 store
__global__ __launch_bounds__(256) void gemm128_kernel(const float* __restrict__ X,
                                                      const float* __restrict__ W,
                                                      unsigned short* __restrict__ H, int n) {
    __shared__ float Ws[64 * 128];
    __shared__ float Xs[64 * 64];
    int t = threadIdx.x;
    int row0 = blockIdx.x * 64;
    int tx = t & 31, ty = t >> 5;
    int c0 = tx * 4, r0 = ty * 8;

    float4 acc[8];
#pragma unroll
    for (int r = 0; r < 8; ++r) acc[r] = make_float4(0.f, 0.f, 0.f, 0.f);

    for (int kp = 0; kp < 2; ++kp) {
        {
            const float4* W4 = (const float4*)(W + kp * 64 * 128);
            float4* Ws4 = (float4*)Ws;
#pragma unroll
            for (int i = 0; i < 8; ++i) Ws4[t + 256 * i] = W4[t + 256 * i];
        }
        {
            float4* Xs4 = (float4*)Xs;
#pragma unroll
            for (int i = 0; i < 4; ++i) {
                int idx = t + 256 * i;
                int r = idx >> 4, c4 = idx & 15;
                int row = row0 + r;
                float4 v = make_float4(0.f, 0.f, 0.f, 0.f);
                if (row < n) v = *(const float4*)(X + (size_t)row * 128 + kp * 64 + c4 * 4);
                Xs4[idx] = v;
            }
        }
        __syncthreads();
        for (int k = 0; k < 64; k += 4) {
            float4 w0 = *(const float4*)&Ws[(k + 0) * 128 + c0];
            float4 w1 = *(const float4*)&Ws[(k + 1) * 128 + c0];
            float4 w2 = *(const float4*)&Ws[(k + 2) * 128 + c0];
            float4 w3 = *(const float4*)&Ws[(k + 3) * 128 + c0];
#pragma unroll
            for (int r = 0; r < 8; ++r) {
                float4 xv = *(const float4*)&Xs[(r0 + r) * 64 + k];
                acc[r].x = fmaf(xv.x, w0.x, fmaf(xv.y, w1.x, fmaf(xv.z, w2.x, fmaf(xv.w, w3.x, acc[r].x))));
                acc[r].y = fmaf(xv.x, w0.y, fmaf(xv.y, w1.y, fmaf(xv.z, w2.y, fmaf(xv.w, w3.y, acc[r].y))));
                acc[r].z = fmaf(xv.x, w0.z, fmaf(xv.y, w1.z, fmaf(xv.z, w2.z, fmaf(xv.w, w3.z, acc[r].z))));
                acc[r].w = fmaf(xv.x, w0.w, fmaf(xv.y, w1.w, fmaf(xv.z, w2.w, fmaf(xv.w, w3.w, acc[r].w))));
            }
        }
        __syncthreads();
    }
#pragma unroll
    for (int r = 0; r < 8; ++r) {
        int row = row0 + r0 + r;
        if (row < n) {
            ushort4v o;
            o.x = f2bf(acc[r].x); o.y = f2bf(acc[r].y);
            o.z = f2bf(acc[r].z); o.w = f2bf(acc[r].w);
            *(ushort4v*)(H + (size_t)row * 128 + c0) = o;
        }
    }
}

// one wave per node; q=lane&15 -> feature octet (ushort8, 16B),
// p=lane>>4 -> edge slot 0..3. One gather instruction = 4 bf16 rows (1KB).
__global__ __launch_bounds__(256) void agg_kernel(const unsigned short* __restrict__ H,
                                                  const int* __restrict__ rowptr,
                                                  const EData* __restrict__ ed,
                                                  const float* __restrict__ dinv,
                                                  const float* __restrict__ b,
                                                  float* __restrict__ out, int n) {
    int gw = (int)((blockIdx.x * blockDim.x + threadIdx.x) >> 6);
    if (gw >= n) return;
    int lane = threadIdx.x & 63;
    int q = lane & 15, p = lane >> 4;
    int beg = rowptr[gw], end = rowptr[gw + 1];
    float di = dinv[gw];

    float acc[8];
#pragma unroll
    for (int j = 0; j < 8; ++j) acc[j] = 0.f;

    int e = beg;
    for (; e + 8 <= end; e += 8) {           // 8 edges, 2 gather instrs in flight
        EData d0 = ed[e + p];
        EData d1 = ed[e + 4 + p];
        ushort8 h0 = *(const ushort8*)(H + (size_t)d0.col * 128 + q * 8);
        ushort8 h1 = *(const ushort8*)(H + (size_t)d1.col * 128 + q * 8);
#pragma unroll
        for (int j = 0; j < 8; ++j) {
            acc[j] = fmaf(d0.w, bf2f(h0[j]), acc[j]);
            acc[j] = fmaf(d1.w, bf2f(h1[j]), acc[j]);
        }
    }
    for (; e < end; e += 4) {                // masked tail, 4 edges/iter
        int idx = e + p;
        bool valid = idx < end;
        EData d0 = ed[valid ? idx : (end - 1)];
        float w = valid ? d0.w : 0.f;
        ushort8 h0 = *(const ushort8*)(H + (size_t)d0.col * 128 + q * 8);
#pragma unroll
        for (int j = 0; j < 8; ++j) acc[j] = fmaf(w, bf2f(h0[j]), acc[j]);
    }
    // combine 4 edge slots: lanes differing in bits 4,5
#pragma unroll
    for (int j = 0; j < 8; ++j) {
        acc[j] += __shfl_xor(acc[j], 16);
        acc[j] += __shfl_xor(acc[j], 32);
    }

    if (p == 0) {   // lanes 0..15 hold the full sum for their octet
        ushort8 hs = *(const ushort8*)(H + (size_t)gw * 128 + q * 8);
        float4 b0 = *(const float4*)(b + q * 8);
        float4 b1 = *(const float4*)(b + q * 8 + 4);
        float o[8];
#pragma unroll
        for (int j = 0; j < 8; ++j) o[j] = (acc[j] + di * bf2f(hs[j])) * di;
        o[0] += b0.x; o[1] += b0.y; o[2] += b0.z; o[3] += b0.w;
        o[4] += b1.x; o[5] += b1.y; o[6] += b1.z; o[7] += b1.w;
        float4 w0 = make_float4(fmaxf(o[0], 0.f), fmaxf(o[1], 0.f), fmaxf(o[2], 0.f), fmaxf(o[3], 0.f));
        float4 w1 = make_float4(fmaxf(o[4], 0.f), fmaxf(o[5], 0.f), fmaxf(o[6], 0.f), fmaxf(o[7], 0.f));
        *(float4*)(out + (size_t)gw * 128 + q * 8)     = w0;
        *(float4*)(out + (size_t)gw * 128 + q * 8 + 4) = w1;
    }
}

extern "C" void kernel_launch(void* const* d_in, const int* in_sizes, int n_in,
                              void* d_out, int out_size, void* d_ws, size_t ws_size,
                              hipStream_t stream) {
    const float* x  = (const float*)d_in[0];
    const int*   ei = (const int*)d_in[1];
    const float* W0 = (const float*)d_in[2];
    const float* b0 = (const float*)d_in[3];
    const float* W1 = (const float*)d_in[4];
    const float* b1 = (const float*)d_in[5];
    const float* W2 = (const float*)d_in[6];
    const float* b2 = (const float*)d_in[7];
    float* out = (float*)d_out;

    int N = in_sizes[0] / 128;
    int E = in_sizes[1] / 2;
    int nb = (N + 255) / 256;

    char* wsb = (char*)d_ws;
    size_t off = 0;
    auto alloc = [&](size_t bytes) -> void* {
        void* p = wsb + off;
        off = (off + bytes + 255) & ~(size_t)255;
        return p;
    };
    int*   cnt    = (int*)  alloc((size_t)N * 4);
    int*   rowptr = (int*)  alloc((size_t)(N + 1) * 4);
    int*   pos    = (int*)  alloc((size_t)N * 4);
    float* dinv   = (float*)alloc((size_t)N * 4);
    int*   bsum   = (int*)  alloc((size_t)nb * 4);
    int*   bpre   = (int*)  alloc((size_t)nb * 4);
    EData* ed     = (EData*)alloc((size_t)E * 8);
    unsigned short* h = (unsigned short*)alloc((size_t)N * 128 * 2);
    float* xA     = (float*)alloc((size_t)N * 128 * 4);

    hipMemsetAsync(cnt, 0, (size_t)N * 4, stream);
    count_kernel<<<(E + 255) / 256, 256, 0, stream>>>(ei, cnt, E);
    block_sum_kernel<<<nb, 256, 0, stream>>>(cnt, bsum, N);
    scan_partials_kernel<<<1, 256, 0, stream>>>(bsum, bpre, rowptr, nb, N);
    scan_write_kernel<<<nb, 256, 0, stream>>>(cnt, bpre, rowptr, pos, dinv, N);
    fill_kernel<<<(E + 255) / 256, 256, 0, stream>>>(ei, pos, ed, dinv, E);

    int gblk = (N + 63) / 64;
    int ablk = (N + 3) / 4;

    gemm128_kernel<<<gblk, 256, 0, stream>>>(x,  W0, h, N);
    agg_kernel<<<ablk, 256, 0, stream>>>(h, rowptr, ed, dinv, b0, xA, N);

    gemm128_kernel<<<gblk, 256, 0, stream>>>(xA, W1, h, N);
    agg_kernel<<<ablk, 256, 0, stream>>>(h, rowptr, ed, dinv, b1, xA, N);

    gemm128_kernel<<<gblk, 256, 0, stream>>>(xA, W2, h, N);
    agg_kernel<<<ablk, 256, 0, stream>>>(h, rowptr, ed, dinv, b2, out, N);
}

// Round 5
// 263.918 us; speedup vs baseline: 2.1225x; 1.1363x over previous
//
#include <hip/hip_runtime.h>

// ---------------------------------------------------------------------------
// 3-layer GCN: per layer  g = dinv * (x@W) [bf16] ;
//              out[i] = relu( dinv[i]*(sum_{e:dst=i} g[src_e] + g[i]) + b )
// CSR-by-dst: count+rank pass (atomic, coalesced rank write) -> scan ->
// atomic-free fill (col only, 4B/edge). Gather-based agg, 16 edges in flight.
// ---------------------------------------------------------------------------

typedef __attribute__((ext_vector_type(8))) unsigned short ushort8;
typedef __attribute__((ext_vector_type(4))) unsigned short ushort4v;

__device__ __forceinline__ unsigned short f2bf(float f) {
    unsigned u = __float_as_uint(f);
    unsigned r = (u + 0x7FFF + ((u >> 16) & 1)) >> 16;   // RNE
    return (unsigned short)r;
}
__device__ __forceinline__ float bf2f(unsigned short s) {
    return __uint_as_float(((unsigned)s) << 16);
}

// count + per-edge rank within its dst bucket (rank write is coalesced)
__global__ void count_rank_kernel(const int* __restrict__ ei, int* __restrict__ cnt,
                                  int* __restrict__ rank, int E) {
    int e = blockIdx.x * blockDim.x + threadIdx.x;
    if (e < E) rank[e] = atomicAdd(&cnt[ei[E + e]], 1);
}

__global__ __launch_bounds__(256) void block_sum_kernel(const int* __restrict__ cnt,
                                                        int* __restrict__ bsum, int n) {
    int i = blockIdx.x * 256 + threadIdx.x;
    int v = (i < n) ? cnt[i] : 0;
#pragma unroll
    for (int off = 32; off; off >>= 1) v += __shfl_down(v, off);
    __shared__ int ws[4];
    int lane = threadIdx.x & 63, w = threadIdx.x >> 6;
    if (lane == 0) ws[w] = v;
    __syncthreads();
    if (threadIdx.x == 0) bsum[blockIdx.x] = ws[0] + ws[1] + ws[2] + ws[3];
}

__global__ __launch_bounds__(256) void scan_partials_kernel(const int* __restrict__ bsum,
                                                            int* __restrict__ bpre,
                                                            int* __restrict__ rowptr,
                                                            int nb, int n) {
    __shared__ int sh[256];
    int t = threadIdx.x;
    int v = (t < nb) ? bsum[t] : 0;
    sh[t] = v;
    __syncthreads();
    for (int off = 1; off < 256; off <<= 1) {
        int u = (t >= off) ? sh[t - off] : 0;
        __syncthreads();
        sh[t] += u;
        __syncthreads();
    }
    if (t < nb) bpre[t] = sh[t] - v;
    if (t == 255) rowptr[n] = sh[255];
}

__global__ __launch_bounds__(256) void scan_write_kernel(const int* __restrict__ cnt,
                                                         const int* __restrict__ bpre,
                                                         int* __restrict__ rowptr,
                                                         float* __restrict__ dinv, int n) {
    __shared__ int sh[256];
    int t = threadIdx.x;
    int i = blockIdx.x * 256 + t;
    int c = (i < n) ? cnt[i] : 0;
    sh[t] = c;
    __syncthreads();
    for (int off = 1; off < 256; off <<= 1) {
        int u = (t >= off) ? sh[t - off] : 0;
        __syncthreads();
        sh[t] += u;
        __syncthreads();
    }
    if (i < n) {
        rowptr[i] = bpre[blockIdx.x] + sh[t] - c;
        dinv[i] = rsqrtf((float)(c + 1));   // +1 self loop
    }
}

// atomic-free scatter: col[rowptr[dst] + rank[e]] = src
__global__ void fill_kernel(const int* __restrict__ ei, const int* __restrict__ rowptr,
                            const int* __restrict__ rank, int* __restrict__ col, int E) {
    int e = blockIdx.x * blockDim.x + threadIdx.x;
    if (e < E) {
        int d = ei[E + e];
        col[rowptr[d] + rank[e]] = ei[e];
    }
}

// G[n,128](bf16) = dinv[row] * (X[n,128](f32) @ W[128,128](f32))
__global__ __launch_bounds__(256) void gemm128_kernel(const float* __restrict__ X,
                                                      const float* __restrict__ W,
                                                      const float* __restrict__ dinv,
                                                      unsigned short* __restrict__ G, int n) {
    __shared__ float Ws[64 * 128];
    __shared__ float Xs[64 * 64];
    int t = threadIdx.x;
    int row0 = blockIdx.x * 64;
    int tx = t & 31, ty = t >> 5;
    int c0 = tx * 4, r0 = ty * 8;

    float4 acc[8];
#pragma unroll
    for (int r = 0; r < 8; ++r) acc[r] = make_float4(0.f, 0.f, 0.f, 0.f);

    for (int kp = 0; kp < 2; ++kp) {
        {
            const float4* W4 = (const float4*)(W + kp * 64 * 128);
            float4* Ws4 = (float4*)Ws;
#pragma unroll
            for (int i = 0; i < 8; ++i) Ws4[t + 256 * i] = W4[t + 256 * i];
        }
        {
            float4* Xs4 = (float4*)Xs;
#pragma unroll
            for (int i = 0; i < 4; ++i) {
                int idx = t + 256 * i;
                int r = idx >> 4, c4 = idx & 15;
                int row = row0 + r;
                float4 v = make_float4(0.f, 0.f, 0.f, 0.f);
                if (row < n) v = *(const float4*)(X + (size_t)row * 128 + kp * 64 + c4 * 4);
                Xs4[idx] = v;
            }
        }
        __syncthreads();
        for (int k = 0; k < 64; k += 4) {
            float4 w0 = *(const float4*)&Ws[(k + 0) * 128 + c0];
            float4 w1 = *(const float4*)&Ws[(k + 1) * 128 + c0];
            float4 w2 = *(const float4*)&Ws[(k + 2) * 128 + c0];
            float4 w3 = *(const float4*)&Ws[(k + 3) * 128 + c0];
#pragma unroll
            for (int r = 0; r < 8; ++r) {
                float4 xv = *(const float4*)&Xs[(r0 + r) * 64 + k];
                acc[r].x = fmaf(xv.x, w0.x, fmaf(xv.y, w1.x, fmaf(xv.z, w2.x, fmaf(xv.w, w3.x, acc[r].x))));
                acc[r].y = fmaf(xv.x, w0.y, fmaf(xv.y, w1.y, fmaf(xv.z, w2.y, fmaf(xv.w, w3.y, acc[r].y))));
                acc[r].z = fmaf(xv.x, w0.z, fmaf(xv.y, w1.z, fmaf(xv.z, w2.z, fmaf(xv.w, w3.z, acc[r].z))));
                acc[r].w = fmaf(xv.x, w0.w, fmaf(xv.y, w1.w, fmaf(xv.z, w2.w, fmaf(xv.w, w3.w, acc[r].w))));
            }
        }
        __syncthreads();
    }
#pragma unroll
    for (int r = 0; r < 8; ++r) {
        int row = row0 + r0 + r;
        if (row < n) {
            float s = dinv[row];
            ushort4v o;
            o.x = f2bf(s * acc[r].x); o.y = f2bf(s * acc[r].y);
            o.z = f2bf(s * acc[r].z); o.w = f2bf(s * acc[r].w);
            *(ushort4v*)(G + (size_t)row * 128 + c0) = o;
        }
    }
}

// one wave per node; q=lane&15 -> feature octet (16B), p=lane>>4 -> edge slot.
// Inner loop: plain adds of gathered g rows; 16 edges (4 gathers) in flight.
__global__ __launch_bounds__(256) void agg_kernel(const unsigned short* __restrict__ G,
                                                  const int* __restrict__ rowptr,
                                                  const int* __restrict__ col,
                                                  const float* __restrict__ dinv,
                                                  const float* __restrict__ b,
                                                  float* __restrict__ out, int n) {
    int gw = (int)((blockIdx.x * blockDim.x + threadIdx.x) >> 6);
    if (gw >= n) return;
    int lane = threadIdx.x & 63;
    int q = lane & 15, p = lane >> 4;
    int beg = rowptr[gw], end = rowptr[gw + 1];
    float di = dinv[gw];

    float acc[8];
#pragma unroll
    for (int j = 0; j < 8; ++j) acc[j] = 0.f;

    int e = beg;
    for (; e + 16 <= end; e += 16) {      // 16 edges: 4 col loads + 4 gathers in flight
        int c0 = col[e + p];
        int c1 = col[e + 4 + p];
        int c2 = col[e + 8 + p];
        int c3 = col[e + 12 + p];
        ushort8 h0 = *(const ushort8*)(G + (size_t)c0 * 128 + q * 8);
        ushort8 h1 = *(const ushort8*)(G + (size_t)c1 * 128 + q * 8);
        ushort8 h2 = *(const ushort8*)(G + (size_t)c2 * 128 + q * 8);
        ushort8 h3 = *(const ushort8*)(G + (size_t)c3 * 128 + q * 8);
#pragma unroll
        for (int j = 0; j < 8; ++j)
            acc[j] += (bf2f(h0[j]) + bf2f(h1[j])) + (bf2f(h2[j]) + bf2f(h3[j]));
    }
    for (; e + 4 <= end; e += 4) {
        int c0 = col[e + p];
        ushort8 h0 = *(const ushort8*)(G + (size_t)c0 * 128 + q * 8);
#pragma unroll
        for (int j = 0; j < 8; ++j) acc[j] += bf2f(h0[j]);
    }
    if (e < end) {                         // masked tail (<4 edges)
        int idx = e + p;
        bool valid = idx < end;
        int c0 = col[valid ? idx : e];
        float w = valid ? 1.f : 0.f;
        ushort8 h0 = *(const ushort8*)(G + (size_t)c0 * 128 + q * 8);
#pragma unroll
        for (int j = 0; j < 8; ++j) acc[j] = fmaf(w, bf2f(h0[j]), acc[j]);
    }
    // combine 4 edge slots (lanes differing in bits 4,5)
#pragma unroll
    for (int j = 0; j < 8; ++j) {
        acc[j] += __shfl_xor(acc[j], 16);
        acc[j] += __shfl_xor(acc[j], 32);
    }

    if (p == 0) {   // lanes 0..15 hold the full sum for their octet
        ushort8 gs = *(const ushort8*)(G + (size_t)gw * 128 + q * 8);
        float4 b0 = *(const float4*)(b + q * 8);
        float4 b1 = *(const float4*)(b + q * 8 + 4);
        float o[8];
#pragma unroll
        for (int j = 0; j < 8; ++j) o[j] = di * (acc[j] + bf2f(gs[j]));
        o[0] += b0.x; o[1] += b0.y; o[2] += b0.z; o[3] += b0.w;
        o[4] += b1.x; o[5] += b1.y; o[6] += b1.z; o[7] += b1.w;
        float4 w0 = make_float4(fmaxf(o[0], 0.f), fmaxf(o[1], 0.f), fmaxf(o[2], 0.f), fmaxf(o[3], 0.f));
        float4 w1 = make_float4(fmaxf(o[4], 0.f), fmaxf(o[5], 0.f), fmaxf(o[6], 0.f), fmaxf(o[7], 0.f));
        *(float4*)(out + (size_t)gw * 128 + q * 8)     = w0;
        *(float4*)(out + (size_t)gw * 128 + q * 8 + 4) = w1;
    }
}

extern "C" void kernel_launch(void* const* d_in, const int* in_sizes, int n_in,
                              void* d_out, int out_size, void* d_ws, size_t ws_size,
                              hipStream_t stream) {
    const float* x  = (const float*)d_in[0];
    const int*   ei = (const int*)d_in[1];
    const float* W0 = (const float*)d_in[2];
    const float* b0 = (const float*)d_in[3];
    const float* W1 = (const float*)d_in[4];
    const float* b1 = (const float*)d_in[5];
    const float* W2 = (const float*)d_in[6];
    const float* b2 = (const float*)d_in[7];
    float* out = (float*)d_out;

    int N = in_sizes[0] / 128;
    int E = in_sizes[1] / 2;
    int nb = (N + 255) / 256;

    char* wsb = (char*)d_ws;
    size_t off = 0;
    auto alloc = [&](size_t bytes) -> void* {
        void* p = wsb + off;
        off = (off + bytes + 255) & ~(size_t)255;
        return p;
    };
    int*   cnt    = (int*)  alloc((size_t)N * 4);
    int*   rowptr = (int*)  alloc((size_t)(N + 1) * 4);
    float* dinv   = (float*)alloc((size_t)N * 4);
    int*   bsum   = (int*)  alloc((size_t)nb * 4);
    int*   bpre   = (int*)  alloc((size_t)nb * 4);
    int*   rank   = (int*)  alloc((size_t)E * 4);
    int*   col    = (int*)  alloc((size_t)E * 4);
    unsigned short* g = (unsigned short*)alloc((size_t)N * 128 * 2);
    float* xA     = (float*)alloc((size_t)N * 128 * 4);

    hipMemsetAsync(cnt, 0, (size_t)N * 4, stream);
    count_rank_kernel<<<(E + 255) / 256, 256, 0, stream>>>(ei, cnt, rank, E);
    block_sum_kernel<<<nb, 256, 0, stream>>>(cnt, bsum, N);
    scan_partials_kernel<<<1, 256, 0, stream>>>(bsum, bpre, rowptr, nb, N);
    scan_write_kernel<<<nb, 256, 0, stream>>>(cnt, bpre, rowptr, dinv, N);
    fill_kernel<<<(E + 255) / 256, 256, 0, stream>>>(ei, rowptr, rank, col, E);

    int gblk = (N + 63) / 64;
    int ablk = (N + 3) / 4;

    gemm128_kernel<<<gblk, 256, 0, stream>>>(x,  W0, dinv, g, N);
    agg_kernel<<<ablk, 256, 0, stream>>>(g, rowptr, col, dinv, b0, xA, N);

    gemm128_kernel<<<gblk, 256, 0, stream>>>(xA, W1, dinv, g, N);
    agg_kernel<<<ablk, 256, 0, stream>>>(g, rowptr, col, dinv, b1, xA, N);

    gemm128_kernel<<<gblk, 256, 0, stream>>>(xA, W2, dinv, g, N);
    agg_kernel<<<ablk, 256, 0, stream>>>(g, rowptr, col, dinv, b2, out, N);
}

// Round 6
// 218.455 us; speedup vs baseline: 2.5642x; 1.2081x over previous
//
#include <hip/hip_runtime.h>

// ---------------------------------------------------------------------------
// 3-layer GCN: per layer  g = dinv * (x@W) [bf16, MFMA] ;
//              out[i] = relu( dinv[i]*(sum_{e:dst=i} g[src_e] + g[i]) + b )
// R5: custom zero kernel (rocclr fill was 41us); GEMM via mfma_f32_16x16x32_bf16
// with pre-packed per-lane W fragments (L1-hot), A-frags straight from global.
// ---------------------------------------------------------------------------

typedef __attribute__((ext_vector_type(8))) unsigned short ushort8;
typedef __attribute__((ext_vector_type(8))) short short8v;
typedef __attribute__((ext_vector_type(4))) float f32x4;

__device__ __forceinline__ unsigned short f2bf(float f) {
    unsigned u = __float_as_uint(f);
    unsigned r = (u + 0x7FFF + ((u >> 16) & 1)) >> 16;   // RNE
    return (unsigned short)r;
}
__device__ __forceinline__ float bf2f(unsigned short s) {
    return __uint_as_float(((unsigned)s) << 16);
}

__global__ __launch_bounds__(256) void zero_kernel(int4* __restrict__ p, int n4) {
    int i = blockIdx.x * 256 + threadIdx.x;
    if (i < n4) p[i] = make_int4(0, 0, 0, 0);
}

// count + per-edge rank within its dst bucket (rank write is coalesced)
__global__ void count_rank_kernel(const int* __restrict__ ei, int* __restrict__ cnt,
                                  int* __restrict__ rank, int E) {
    int e = blockIdx.x * blockDim.x + threadIdx.x;
    if (e < E) rank[e] = atomicAdd(&cnt[ei[E + e]], 1);
}

__global__ __launch_bounds__(256) void block_sum_kernel(const int* __restrict__ cnt,
                                                        int* __restrict__ bsum, int n) {
    int i = blockIdx.x * 256 + threadIdx.x;
    int v = (i < n) ? cnt[i] : 0;
#pragma unroll
    for (int off = 32; off; off >>= 1) v += __shfl_down(v, off);
    __shared__ int ws[4];
    int lane = threadIdx.x & 63, w = threadIdx.x >> 6;
    if (lane == 0) ws[w] = v;
    __syncthreads();
    if (threadIdx.x == 0) bsum[blockIdx.x] = ws[0] + ws[1] + ws[2] + ws[3];
}

__global__ __launch_bounds__(256) void scan_partials_kernel(const int* __restrict__ bsum,
                                                            int* __restrict__ bpre,
                                                            int* __restrict__ rowptr,
                                                            int nb, int n) {
    __shared__ int sh[256];
    int t = threadIdx.x;
    int v = (t < nb) ? bsum[t] : 0;
    sh[t] = v;
    __syncthreads();
    for (int off = 1; off < 256; off <<= 1) {
        int u = (t >= off) ? sh[t - off] : 0;
        __syncthreads();
        sh[t] += u;
        __syncthreads();
    }
    if (t < nb) bpre[t] = sh[t] - v;
    if (t == 255) rowptr[n] = sh[255];
}

__global__ __launch_bounds__(256) void scan_write_kernel(const int* __restrict__ cnt,
                                                         const int* __restrict__ bpre,
                                                         int* __restrict__ rowptr,
                                                         float* __restrict__ dinv, int n) {
    __shared__ int sh[256];
    int t = threadIdx.x;
    int i = blockIdx.x * 256 + t;
    int c = (i < n) ? cnt[i] : 0;
    sh[t] = c;
    __syncthreads();
    for (int off = 1; off < 256; off <<= 1) {
        int u = (t >= off) ? sh[t - off] : 0;
        __syncthreads();
        sh[t] += u;
        __syncthreads();
    }
    if (i < n) {
        rowptr[i] = bpre[blockIdx.x] + sh[t] - c;
        dinv[i] = rsqrtf((float)(c + 1));   // +1 self loop
    }
}

// atomic-free scatter: col[rowptr[dst] + rank[e]] = src
__global__ void fill_kernel(const int* __restrict__ ei, const int* __restrict__ rowptr,
                            const int* __restrict__ rank, int* __restrict__ col, int E) {
    int e = blockIdx.x * blockDim.x + threadIdx.x;
    if (e < E) {
        int d = ei[E + e];
        col[rowptr[d] + rank[e]] = ei[e];
    }
}

// Pack W[128][128] fp32 into per-lane bf16 B-fragments:
// Wfrag[(c*4+ks)*64 + l] = { W[ks*32+(l>>4)*8+j][c*16+(l&15)] : j=0..7 }
// 2048 threads per W (8 blocks x 256).
__global__ __launch_bounds__(256) void wprep_kernel(const float* __restrict__ W,
                                                    short* __restrict__ Wfrag) {
    int idx = blockIdx.x * 256 + threadIdx.x;   // 0..2047
    int l = idx & 63;
    int cks = idx >> 6;                          // 0..31
    int ks = cks & 3, c = cks >> 2;
    int col = c * 16 + (l & 15);
    int k0 = ks * 32 + (l >> 4) * 8;
    short8v o;
#pragma unroll
    for (int j = 0; j < 8; ++j) o[j] = (short)f2bf(W[(size_t)(k0 + j) * 128 + col]);
    ((short8v*)Wfrag)[idx] = o;
}

// G[n,128](bf16) = dinv[row] * (X[n,128](f32->bf16) @ W) via MFMA 16x16x32.
// 4 waves/block, 16 rows/wave. A-frag: 8 contiguous K fp32 from global, cvt.
// B-frag: prepacked Wfrag, coalesced 16B, L1-hot (32KB).
// C/D layout: col=lane&15, row=(lane>>4)*4+reg  [learn_hip m89].
__global__ __launch_bounds__(256) void gemm_mfma_kernel(const float* __restrict__ X,
                                                        const short* __restrict__ Wfrag,
                                                        const float* __restrict__ dinv,
                                                        unsigned short* __restrict__ G, int n) {
    int t = threadIdx.x;
    int wv = t >> 6, l = t & 63;
    int row0 = blockIdx.x * 64 + wv * 16;
    int r = l & 15, half = l >> 4;          // half in 0..3
    int arow = row0 + r;
    bool rok = arow < n;

    f32x4 acc[8];
#pragma unroll
    for (int c = 0; c < 8; ++c) acc[c] = (f32x4){0.f, 0.f, 0.f, 0.f};

    const short8v* WF = (const short8v*)Wfrag;

#pragma unroll
    for (int ks = 0; ks < 4; ++ks) {
        short8v a = (short8v){0, 0, 0, 0, 0, 0, 0, 0};
        if (rok) {
            const float4* xp = (const float4*)(X + (size_t)arow * 128 + ks * 32 + half * 8);
            float4 x0 = xp[0], x1 = xp[1];
            a[0] = (short)f2bf(x0.x); a[1] = (short)f2bf(x0.y);
            a[2] = (short)f2bf(x0.z); a[3] = (short)f2bf(x0.w);
            a[4] = (short)f2bf(x1.x); a[5] = (short)f2bf(x1.y);
            a[6] = (short)f2bf(x1.z); a[7] = (short)f2bf(x1.w);
        }
#pragma unroll
        for (int c = 0; c < 8; ++c) {
            short8v b = WF[(c * 4 + ks) * 64 + l];
            acc[c] = __builtin_amdgcn_mfma_f32_16x16x32_bf16(a, b, acc[c], 0, 0, 0);
        }
    }

    float ds[4];
    int orow[4];
#pragma unroll
    for (int i = 0; i < 4; ++i) {
        orow[i] = row0 + half * 4 + i;
        ds[i] = (orow[i] < n) ? dinv[orow[i]] : 0.f;
    }
#pragma unroll
    for (int c = 0; c < 8; ++c) {
#pragma unroll
        for (int i = 0; i < 4; ++i) {
            if (orow[i] < n)
                G[(size_t)orow[i] * 128 + c * 16 + r] = f2bf(ds[i] * acc[c][i]);
        }
    }
}

// one wave per node; q=lane&15 -> feature octet (16B), p=lane>>4 -> edge slot.
__global__ __launch_bounds__(256) void agg_kernel(const unsigned short* __restrict__ G,
                                                  const int* __restrict__ rowptr,
                                                  const int* __restrict__ col,
                                                  const float* __restrict__ dinv,
                                                  const float* __restrict__ b,
                                                  float* __restrict__ out, int n) {
    int gw = (int)((blockIdx.x * blockDim.x + threadIdx.x) >> 6);
    if (gw >= n) return;
    int lane = threadIdx.x & 63;
    int q = lane & 15, p = lane >> 4;
    int beg = rowptr[gw], end = rowptr[gw + 1];
    float di = dinv[gw];

    float acc[8];
#pragma unroll
    for (int j = 0; j < 8; ++j) acc[j] = 0.f;

    int e = beg;
    for (; e + 16 <= end; e += 16) {
        int c0 = col[e + p];
        int c1 = col[e + 4 + p];
        int c2 = col[e + 8 + p];
        int c3 = col[e + 12 + p];
        ushort8 h0 = *(const ushort8*)(G + (size_t)c0 * 128 + q * 8);
        ushort8 h1 = *(const ushort8*)(G + (size_t)c1 * 128 + q * 8);
        ushort8 h2 = *(const ushort8*)(G + (size_t)c2 * 128 + q * 8);
        ushort8 h3 = *(const ushort8*)(G + (size_t)c3 * 128 + q * 8);
#pragma unroll
        for (int j = 0; j < 8; ++j)
            acc[j] += (bf2f(h0[j]) + bf2f(h1[j])) + (bf2f(h2[j]) + bf2f(h3[j]));
    }
    for (; e + 4 <= end; e += 4) {
        int c0 = col[e + p];
        ushort8 h0 = *(const ushort8*)(G + (size_t)c0 * 128 + q * 8);
#pragma unroll
        for (int j = 0; j < 8; ++j) acc[j] += bf2f(h0[j]);
    }
    if (e < end) {
        int idx = e + p;
        bool valid = idx < end;
        int c0 = col[valid ? idx : e];
        float w = valid ? 1.f : 0.f;
        ushort8 h0 = *(const ushort8*)(G + (size_t)c0 * 128 + q * 8);
#pragma unroll
        for (int j = 0; j < 8; ++j) acc[j] = fmaf(w, bf2f(h0[j]), acc[j]);
    }
#pragma unroll
    for (int j = 0; j < 8; ++j) {
        acc[j] += __shfl_xor(acc[j], 16);
        acc[j] += __shfl_xor(acc[j], 32);
    }

    if (p == 0) {
        ushort8 gs = *(const ushort8*)(G + (size_t)gw * 128 + q * 8);
        float4 b0 = *(const float4*)(b + q * 8);
        float4 b1 = *(const float4*)(b + q * 8 + 4);
        float o[8];
#pragma unroll
        for (int j = 0; j < 8; ++j) o[j] = di * (acc[j] + bf2f(gs[j]));
        o[0] += b0.x; o[1] += b0.y; o[2] += b0.z; o[3] += b0.w;
        o[4] += b1.x; o[5] += b1.y; o[6] += b1.z; o[7] += b1.w;
        float4 w0 = make_float4(fmaxf(o[0], 0.f), fmaxf(o[1], 0.f), fmaxf(o[2], 0.f), fmaxf(o[3], 0.f));
        float4 w1 = make_float4(fmaxf(o[4], 0.f), fmaxf(o[5], 0.f), fmaxf(o[6], 0.f), fmaxf(o[7], 0.f));
        *(float4*)(out + (size_t)gw * 128 + q * 8)     = w0;
        *(float4*)(out + (size_t)gw * 128 + q * 8 + 4) = w1;
    }
}

extern "C" void kernel_launch(void* const* d_in, const int* in_sizes, int n_in,
                              void* d_out, int out_size, void* d_ws, size_t ws_size,
                              hipStream_t stream) {
    const float* x  = (const float*)d_in[0];
    const int*   ei = (const int*)d_in[1];
    const float* W0 = (const float*)d_in[2];
    const float* b0 = (const float*)d_in[3];
    const float* W1 = (const float*)d_in[4];
    const float* b1 = (const float*)d_in[5];
    const float* W2 = (const float*)d_in[6];
    const float* b2 = (const float*)d_in[7];
    float* out = (float*)d_out;

    int N = in_sizes[0] / 128;
    int E = in_sizes[1] / 2;
    int nb = (N + 255) / 256;

    char* wsb = (char*)d_ws;
    size_t off = 0;
    auto alloc = [&](size_t bytes) -> void* {
        void* p = wsb + off;
        off = (off + bytes + 255) & ~(size_t)255;
        return p;
    };
    int*   cnt    = (int*)  alloc((size_t)N * 4);
    int*   rowptr = (int*)  alloc((size_t)(N + 1) * 4);
    float* dinv   = (float*)alloc((size_t)N * 4);
    int*   bsum   = (int*)  alloc((size_t)nb * 4);
    int*   bpre   = (int*)  alloc((size_t)nb * 4);
    int*   rank   = (int*)  alloc((size_t)E * 4);
    int*   col    = (int*)  alloc((size_t)E * 4);
    unsigned short* g = (unsigned short*)alloc((size_t)N * 128 * 2);
    float* xA     = (float*)alloc((size_t)N * 128 * 4);
    short* wf0    = (short*)alloc(128 * 128 * 2);
    short* wf1    = (short*)alloc(128 * 128 * 2);
    short* wf2    = (short*)alloc(128 * 128 * 2);

    int n4 = (N + 3) / 4;   // N*4 bytes / 16
    zero_kernel<<<(n4 + 255) / 256, 256, 0, stream>>>((int4*)cnt, n4);
    count_rank_kernel<<<(E + 255) / 256, 256, 0, stream>>>(ei, cnt, rank, E);
    block_sum_kernel<<<nb, 256, 0, stream>>>(cnt, bsum, N);
    scan_partials_kernel<<<1, 256, 0, stream>>>(bsum, bpre, rowptr, nb, N);
    scan_write_kernel<<<nb, 256, 0, stream>>>(cnt, bpre, rowptr, dinv, N);
    fill_kernel<<<(E + 255) / 256, 256, 0, stream>>>(ei, rowptr, rank, col, E);
    wprep_kernel<<<8, 256, 0, stream>>>(W0, wf0);
    wprep_kernel<<<8, 256, 0, stream>>>(W1, wf1);
    wprep_kernel<<<8, 256, 0, stream>>>(W2, wf2);

    int gblk = (N + 63) / 64;
    int ablk = (N + 3) / 4;

    gemm_mfma_kernel<<<gblk, 256, 0, stream>>>(x,  wf0, dinv, g, N);
    agg_kernel<<<ablk, 256, 0, stream>>>(g, rowptr, col, dinv, b0, xA, N);

    gemm_mfma_kernel<<<gblk, 256, 0, stream>>>(xA, wf1, dinv, g, N);
    agg_kernel<<<ablk, 256, 0, stream>>>(g, rowptr, col, dinv, b1, xA, N);

    gemm_mfma_kernel<<<gblk, 256, 0, stream>>>(xA, wf2, dinv, g, N);
    agg_kernel<<<ablk, 256, 0, stream>>>(g, rowptr, col, dinv, b2, out, N);
}

// Round 7
// 214.003 us; speedup vs baseline: 2.6176x; 1.0208x over previous
//
#include <hip/hip_runtime.h>

// ---------------------------------------------------------------------------
// 3-layer GCN: per layer  g = dinv * (x@W) [bf16, MFMA 16x16x32] ;
//              out[i] = relu( dinv[i]*(sum_{e:dst=i} g[src_e] + g[i]) + b )
// R6: agg = masked 2-stage pipelined gather (8 edges/stage, robust to Poisson
// degree); inter-layer activations stored bf16 (bit-identical, half traffic);
// single wprep launch.
// ---------------------------------------------------------------------------

typedef __attribute__((ext_vector_type(8))) unsigned short ushort8;
typedef __attribute__((ext_vector_type(8))) short short8v;
typedef __attribute__((ext_vector_type(4))) float f32x4;

__device__ __forceinline__ unsigned short f2bf(float f) {
    unsigned u = __float_as_uint(f);
    unsigned r = (u + 0x7FFF + ((u >> 16) & 1)) >> 16;   // RNE
    return (unsigned short)r;
}
__device__ __forceinline__ float bf2f(unsigned short s) {
    return __uint_as_float(((unsigned)s) << 16);
}

__global__ __launch_bounds__(256) void zero_kernel(int4* __restrict__ p, int n4) {
    int i = blockIdx.x * 256 + threadIdx.x;
    if (i < n4) p[i] = make_int4(0, 0, 0, 0);
}

__global__ void count_rank_kernel(const int* __restrict__ ei, int* __restrict__ cnt,
                                  int* __restrict__ rank, int E) {
    int e = blockIdx.x * blockDim.x + threadIdx.x;
    if (e < E) rank[e] = atomicAdd(&cnt[ei[E + e]], 1);
}

__global__ __launch_bounds__(256) void block_sum_kernel(const int* __restrict__ cnt,
                                                        int* __restrict__ bsum, int n) {
    int i = blockIdx.x * 256 + threadIdx.x;
    int v = (i < n) ? cnt[i] : 0;
#pragma unroll
    for (int off = 32; off; off >>= 1) v += __shfl_down(v, off);
    __shared__ int ws[4];
    int lane = threadIdx.x & 63, w = threadIdx.x >> 6;
    if (lane == 0) ws[w] = v;
    __syncthreads();
    if (threadIdx.x == 0) bsum[blockIdx.x] = ws[0] + ws[1] + ws[2] + ws[3];
}

__global__ __launch_bounds__(256) void scan_partials_kernel(const int* __restrict__ bsum,
                                                            int* __restrict__ bpre,
                                                            int* __restrict__ rowptr,
                                                            int nb, int n) {
    __shared__ int sh[256];
    int t = threadIdx.x;
    int v = (t < nb) ? bsum[t] : 0;
    sh[t] = v;
    __syncthreads();
    for (int off = 1; off < 256; off <<= 1) {
        int u = (t >= off) ? sh[t - off] : 0;
        __syncthreads();
        sh[t] += u;
        __syncthreads();
    }
    if (t < nb) bpre[t] = sh[t] - v;
    if (t == 255) rowptr[n] = sh[255];
}

__global__ __launch_bounds__(256) void scan_write_kernel(const int* __restrict__ cnt,
                                                         const int* __restrict__ bpre,
                                                         int* __restrict__ rowptr,
                                                         float* __restrict__ dinv, int n) {
    __shared__ int sh[256];
    int t = threadIdx.x;
    int i = blockIdx.x * 256 + t;
    int c = (i < n) ? cnt[i] : 0;
    sh[t] = c;
    __syncthreads();
    for (int off = 1; off < 256; off <<= 1) {
        int u = (t >= off) ? sh[t - off] : 0;
        __syncthreads();
        sh[t] += u;
        __syncthreads();
    }
    if (i < n) {
        rowptr[i] = bpre[blockIdx.x] + sh[t] - c;
        dinv[i] = rsqrtf((float)(c + 1));   // +1 self loop
    }
}

__global__ void fill_kernel(const int* __restrict__ ei, const int* __restrict__ rowptr,
                            const int* __restrict__ rank, int* __restrict__ col, int E) {
    int e = blockIdx.x * blockDim.x + threadIdx.x;
    if (e < E) {
        int d = ei[E + e];
        col[rowptr[d] + rank[e]] = ei[e];
    }
}

// Pack 3 W[128][128] fp32 into per-lane bf16 B-fragments (one launch, 24 blocks):
// Wfrag[(c*4+ks)*64 + l] = { W[ks*32+(l>>4)*8+j][c*16+(l&15)] : j=0..7 }
__global__ __launch_bounds__(256) void wprep_kernel(const float* __restrict__ W0,
                                                    const float* __restrict__ W1,
                                                    const float* __restrict__ W2,
                                                    short* __restrict__ F0,
                                                    short* __restrict__ F1,
                                                    short* __restrict__ F2) {
    int which = blockIdx.x >> 3;
    const float* W = which == 0 ? W0 : (which == 1 ? W1 : W2);
    short* Wfrag   = which == 0 ? F0 : (which == 1 ? F1 : F2);
    int idx = (blockIdx.x & 7) * 256 + threadIdx.x;   // 0..2047
    int l = idx & 63;
    int cks = idx >> 6;
    int ks = cks & 3, c = cks >> 2;
    int col = c * 16 + (l & 15);
    int k0 = ks * 32 + (l >> 4) * 8;
    short8v o;
#pragma unroll
    for (int j = 0; j < 8; ++j) o[j] = (short)f2bf(W[(size_t)(k0 + j) * 128 + col]);
    ((short8v*)Wfrag)[idx] = o;
}

// G = dinv * (X @ W) via MFMA 16x16x32 bf16.
// IN_BF16: X is bf16 (ushort) rows; else fp32 rows (layer 1).
// 4 waves/block, 16 rows/wave; B-frags prepacked (L1-hot 32KB).
// C/D layout: col=lane&15, row=(lane>>4)*4+reg  [learn_hip m89].
template <bool IN_BF16>
__global__ __launch_bounds__(256) void gemm_mfma_kernel(const void* __restrict__ Xv,
                                                        const short* __restrict__ Wfrag,
                                                        const float* __restrict__ dinv,
                                                        unsigned short* __restrict__ G, int n) {
    int t = threadIdx.x;
    int wv = t >> 6, l = t & 63;
    int row0 = blockIdx.x * 64 + wv * 16;
    int r = l & 15, half = l >> 4;
    int arow = row0 + r;
    bool rok = arow < n;

    f32x4 acc[8];
#pragma unroll
    for (int c = 0; c < 8; ++c) acc[c] = (f32x4){0.f, 0.f, 0.f, 0.f};

    const short8v* WF = (const short8v*)Wfrag;

#pragma unroll
    for (int ks = 0; ks < 4; ++ks) {
        short8v a = (short8v){0, 0, 0, 0, 0, 0, 0, 0};
        if (rok) {
            if (IN_BF16) {
                const unsigned short* X = (const unsigned short*)Xv;
                a = *(const short8v*)(X + (size_t)arow * 128 + ks * 32 + half * 8);
            } else {
                const float* X = (const float*)Xv;
                const float4* xp = (const float4*)(X + (size_t)arow * 128 + ks * 32 + half * 8);
                float4 x0 = xp[0], x1 = xp[1];
                a[0] = (short)f2bf(x0.x); a[1] = (short)f2bf(x0.y);
                a[2] = (short)f2bf(x0.z); a[3] = (short)f2bf(x0.w);
                a[4] = (short)f2bf(x1.x); a[5] = (short)f2bf(x1.y);
                a[6] = (short)f2bf(x1.z); a[7] = (short)f2bf(x1.w);
            }
        }
#pragma unroll
        for (int c = 0; c < 8; ++c) {
            short8v b = WF[(c * 4 + ks) * 64 + l];
            acc[c] = __builtin_amdgcn_mfma_f32_16x16x32_bf16(a, b, acc[c], 0, 0, 0);
        }
    }

    float ds[4];
    int orow[4];
#pragma unroll
    for (int i = 0; i < 4; ++i) {
        orow[i] = row0 + half * 4 + i;
        ds[i] = (orow[i] < n) ? dinv[orow[i]] : 0.f;
    }
#pragma unroll
    for (int c = 0; c < 8; ++c) {
#pragma unroll
        for (int i = 0; i < 4; ++i) {
            if (orow[i] < n)
                G[(size_t)orow[i] * 128 + c * 16 + r] = f2bf(ds[i] * acc[c][i]);
        }
    }
}

// one wave per node; q=lane&15 -> feature octet (16B), p=lane>>4 -> edge slot.
// Masked 2-stage software pipeline, 8 edges/stage: gathers for stage s+2 are
// in flight while stage s is consumed; robust for any degree (Poisson ~16).
template <bool OUT_BF16>
__global__ __launch_bounds__(256) void agg_kernel(const unsigned short* __restrict__ G,
                                                  const int* __restrict__ rowptr,
                                                  const int* __restrict__ col,
                                                  const float* __restrict__ dinv,
                                                  const float* __restrict__ b,
                                                  void* __restrict__ outv, int n) {
    int gw = (int)((blockIdx.x * blockDim.x + threadIdx.x) >> 6);
    if (gw >= n) return;
    int lane = threadIdx.x & 63;
    int q = lane & 15, p = lane >> 4;
    int beg = rowptr[gw], end = rowptr[gw + 1];
    float di = dinv[gw];

    // self-loop row: issue early, overlaps the pipeline fill
    ushort8 gs = *(const ushort8*)(G + (size_t)gw * 128 + q * 8);

    float acc[8];
#pragma unroll
    for (int j = 0; j < 8; ++j) acc[j] = 0.f;

    int deg = end - beg;
    int nit = (deg + 7) >> 3;   // stages of 8 edges

    ushort8 h0a, h1a, h0b, h1b;
    float m0a = 0.f, m1a = 0.f, m0b = 0.f, m1b = 0.f;

    auto issue = [&](int s, ushort8& h0, ushort8& h1, float& m0, float& m1) {
        int i0 = beg + s * 8 + p;
        int i1 = i0 + 4;
        bool v0 = i0 < end, v1 = i1 < end;
        int c0 = col[v0 ? i0 : 0];
        int c1 = col[v1 ? i1 : 0];
        m0 = v0 ? 1.f : 0.f;
        m1 = v1 ? 1.f : 0.f;
        h0 = *(const ushort8*)(G + (size_t)c0 * 128 + q * 8);
        h1 = *(const ushort8*)(G + (size_t)c1 * 128 + q * 8);
    };

    if (nit > 0) issue(0, h0a, h1a, m0a, m1a);
    if (nit > 1) issue(1, h0b, h1b, m0b, m1b);
    for (int s = 0; s < nit; ++s) {
#pragma unroll
        for (int j = 0; j < 8; ++j) {
            acc[j] = fmaf(m0a, bf2f(h0a[j]), acc[j]);
            acc[j] = fmaf(m1a, bf2f(h1a[j]), acc[j]);
        }
        h0a = h0b; h1a = h1b; m0a = m0b; m1a = m1b;
        if (s + 2 < nit) issue(s + 2, h0b, h1b, m0b, m1b);
    }

    // combine 4 edge slots (lanes differing in bits 4,5)
#pragma unroll
    for (int j = 0; j < 8; ++j) {
        acc[j] += __shfl_xor(acc[j], 16);
        acc[j] += __shfl_xor(acc[j], 32);
    }

    if (p == 0) {   // lanes 0..15 hold the full sum for their octet
        float4 b0 = *(const float4*)(b + q * 8);
        float4 b1 = *(const float4*)(b + q * 8 + 4);
        float o[8];
#pragma unroll
        for (int j = 0; j < 8; ++j) o[j] = di * (acc[j] + bf2f(gs[j]));
        o[0] += b0.x; o[1] += b0.y; o[2] += b0.z; o[3] += b0.w;
        o[4] += b1.x; o[5] += b1.y; o[6] += b1.z; o[7] += b1.w;
#pragma unroll
        for (int j = 0; j < 8; ++j) o[j] = fmaxf(o[j], 0.f);
        if (OUT_BF16) {
            ushort8 ov;
#pragma unroll
            for (int j = 0; j < 8; ++j) ov[j] = f2bf(o[j]);
            *(ushort8*)((unsigned short*)outv + (size_t)gw * 128 + q * 8) = ov;
        } else {
            float* out = (float*)outv;
            *(float4*)(out + (size_t)gw * 128 + q * 8)     = make_float4(o[0], o[1], o[2], o[3]);
            *(float4*)(out + (size_t)gw * 128 + q * 8 + 4) = make_float4(o[4], o[5], o[6], o[7]);
        }
    }
}

extern "C" void kernel_launch(void* const* d_in, const int* in_sizes, int n_in,
                              void* d_out, int out_size, void* d_ws, size_t ws_size,
                              hipStream_t stream) {
    const float* x  = (const float*)d_in[0];
    const int*   ei = (const int*)d_in[1];
    const float* W0 = (const float*)d_in[2];
    const float* b0 = (const float*)d_in[3];
    const float* W1 = (const float*)d_in[4];
    const float* b1 = (const float*)d_in[5];
    const float* W2 = (const float*)d_in[6];
    const float* b2 = (const float*)d_in[7];
    float* out = (float*)d_out;

    int N = in_sizes[0] / 128;
    int E = in_sizes[1] / 2;
    int nb = (N + 255) / 256;

    char* wsb = (char*)d_ws;
    size_t off = 0;
    auto alloc = [&](size_t bytes) -> void* {
        void* p = wsb + off;
        off = (off + bytes + 255) & ~(size_t)255;
        return p;
    };
    int*   cnt    = (int*)  alloc((size_t)N * 4);
    int*   rowptr = (int*)  alloc((size_t)(N + 1) * 4);
    float* dinv   = (float*)alloc((size_t)N * 4);
    int*   bsum   = (int*)  alloc((size_t)nb * 4);
    int*   bpre   = (int*)  alloc((size_t)nb * 4);
    int*   rank   = (int*)  alloc((size_t)E * 4);
    int*   col    = (int*)  alloc((size_t)E * 4);
    unsigned short* g  = (unsigned short*)alloc((size_t)N * 128 * 2);
    unsigned short* xB = (unsigned short*)alloc((size_t)N * 128 * 2);
    short* wf0    = (short*)alloc(128 * 128 * 2);
    short* wf1    = (short*)alloc(128 * 128 * 2);
    short* wf2    = (short*)alloc(128 * 128 * 2);

    int n4 = (N + 3) / 4;
    zero_kernel<<<(n4 + 255) / 256, 256, 0, stream>>>((int4*)cnt, n4);
    count_rank_kernel<<<(E + 255) / 256, 256, 0, stream>>>(ei, cnt, rank, E);
    block_sum_kernel<<<nb, 256, 0, stream>>>(cnt, bsum, N);
    scan_partials_kernel<<<1, 256, 0, stream>>>(bsum, bpre, rowptr, nb, N);
    scan_write_kernel<<<nb, 256, 0, stream>>>(cnt, bpre, rowptr, dinv, N);
    fill_kernel<<<(E + 255) / 256, 256, 0, stream>>>(ei, rowptr, rank, col, E);
    wprep_kernel<<<24, 256, 0, stream>>>(W0, W1, W2, wf0, wf1, wf2);

    int gblk = (N + 63) / 64;
    int ablk = (N + 3) / 4;

    gemm_mfma_kernel<false><<<gblk, 256, 0, stream>>>(x,  wf0, dinv, g, N);
    agg_kernel<true><<<ablk, 256, 0, stream>>>(g, rowptr, col, dinv, b0, xB, N);

    gemm_mfma_kernel<true><<<gblk, 256, 0, stream>>>(xB, wf1, dinv, g, N);
    agg_kernel<true><<<ablk, 256, 0, stream>>>(g, rowptr, col, dinv, b1, xB, N);

    gemm_mfma_kernel<true><<<gblk, 256, 0, stream>>>(xB, wf2, dinv, g, N);
    agg_kernel<false><<<ablk, 256, 0, stream>>>(g, rowptr, col, dinv, b2, out, N);
}